// Round 17
// baseline (68.904 us; speedup 1.0000x reference)
//
#include <hip/hip_runtime.h>
#include <hip/hip_bf16.h>
#include <stdint.h>

typedef unsigned short u16;
typedef __attribute__((ext_vector_type(8))) unsigned short u16x8;
typedef __attribute__((ext_vector_type(8))) __bf16 bf16x8;
typedef __attribute__((ext_vector_type(4))) float f32x4;

__device__ __forceinline__ u16 f2bf(float f) {
    uint32_t u = __builtin_bit_cast(uint32_t, f);
    u = (u + 0x7fffu + ((u >> 16) & 1u)) >> 16;
    return (u16)u;
}

__device__ __forceinline__ float bf2f(u16 v) {
    return __builtin_bit_cast(float, (uint32_t)v << 16);
}

__device__ __forceinline__ u16x8 pack8u(f32x4 a, f32x4 b) {
    u16x8 o;
    o[0] = f2bf(a[0]); o[1] = f2bf(a[1]); o[2] = f2bf(a[2]); o[3] = f2bf(a[3]);
    o[4] = f2bf(b[0]); o[5] = f2bf(b[1]); o[6] = f2bf(b[2]); o[7] = f2bf(b[3]);
    return o;
}

// ---------------- prep: H12bT [128][2048] bf16  +  H34T [1024][64] bf16 (one launch)
__global__ __launch_bounds__(256) void prep_kernel(const float* __restrict__ f0,
                                                   const float* __restrict__ f1,
                                                   const float* __restrict__ f2,
                                                   const float* __restrict__ f3,
                                                   u16* __restrict__ H12bT,
                                                   u16* __restrict__ H34T) {
    int gid = blockIdx.x * 256 + threadIdx.x;       // 0..327679
    if (gid < 262144) {
        int rc = gid >> 11;                          // p*64 + e
        int k  = gid & 2047;                         // i1*32 + j2
        int p = rc >> 6, e = rc & 63;
        int a = e >> 3, b = e & 7;
        int i1 = k >> 5, i2 = ((k & 31) << 1) | p;
        float s = 0.f;
#pragma unroll
        for (int m = 0; m < 8; m++)
            s += f0[a * 512 + i1 * 8 + m] * f1[m * 512 + i2 * 8 + b];
        H12bT[gid] = f2bf(s);
    } else {
        int g = gid - 262144;                        // 0..65535
        int c = g >> 6;
        int e = g & 63;
        int a = e >> 3, b = e & 7;
        int i3 = c >> 4, i4 = c & 15;
        float s = 0.f;
#pragma unroll
        for (int cc = 0; cc < 8; cc++)
            s += f2[b * 512 + i3 * 8 + cc] * f3[cc * 128 + i4 * 8 + a];
        H34T[c * 64 + e] = f2bf(s);
    }
}

// ---------------- K1F: Y[8192][128] bf16 = x @ H12bT^T, no split-K.
// grid 256, block 512 (8 waves). 32 rows/block, K=2048 in 8 chunks of 256.
// Staging = k2r-geometry contiguous reads (4 indep f32x4/thread), T14 split
// (loads issued before compute, ds_write after barrier), double-buffered LDS
// bf16 tile with 16B-granule XOR swizzle (write+read matched involution).
__global__ __launch_bounds__(512) void k1_kernel(const float* __restrict__ x,
                                                 const u16* __restrict__ H12bT,
                                                 u16* __restrict__ Y) {
    __shared__ u16 Xb[2][32][256];   // 2 x 16 KB bf16
    int tid = threadIdx.x, lane = tid & 63, w = tid >> 6;
    int lm = lane & 15, lkE = (lane >> 4) << 3;
    int r0 = blockIdx.x * 32;
    int wr = w >> 2, jc = w & 3;     // wave: rows wr*16..+15, cols jc*32..+31

    // staging geometry: thread t -> row t>>4, f32 cols (t&15)*16 .. +15 (contiguous 64B)
    int srow = tid >> 4;
    int sc0 = (tid & 15) << 4;
    const float* xs = x + (size_t)(r0 + srow) * 2048 + sc0;
    int wb0 = srow * 512 + (((sc0 << 1)) ^ ((srow & 7) << 4));        // byte off, h=0
    int wb1 = srow * 512 + (((sc0 << 1) + 16) ^ ((srow & 7) << 4));   // byte off, h=1

    f32x4 acc[2];
    acc[0] = (f32x4){0.f, 0.f, 0.f, 0.f};
    acc[1] = (f32x4){0.f, 0.f, 0.f, 0.f};

    // prologue: stage chunk 0 into buf 0
    {
        f32x4 v0 = *(const f32x4*)(xs);
        f32x4 v1 = *(const f32x4*)(xs + 4);
        f32x4 v2 = *(const f32x4*)(xs + 8);
        f32x4 v3 = *(const f32x4*)(xs + 12);
        *(u16x8*)((char*)&Xb[0][0][0] + wb0) = pack8u(v0, v1);
        *(u16x8*)((char*)&Xb[0][0][0] + wb1) = pack8u(v2, v3);
    }
    __syncthreads();

    int ar = wr * 16 + lm;                           // A-frag row
    int asx = (ar & 7) << 4;
    const u16* bp = H12bT + (size_t)(jc * 32 + lm) * 2048 + lkE;

#pragma unroll 1
    for (int kt = 0; kt < 8; ++kt) {
        const char* abase = (const char*)&Xb[kt & 1][0][0] + ar * 512;
        // T14: issue next chunk's loads BEFORE compute (held in 16 VGPR)
        f32x4 v0, v1, v2, v3;
        if (kt + 1 < 8) {
            const float* xn = xs + (kt + 1) * 256;
            v0 = *(const f32x4*)(xn);
            v1 = *(const f32x4*)(xn + 4);
            v2 = *(const f32x4*)(xn + 8);
            v3 = *(const f32x4*)(xn + 12);
        }
        // compute chunk kt: 8 kc x {1 LDS A-frag, 2 L2 B-frags, 2 MFMA}
#pragma unroll
        for (int kc = 0; kc < 8; ++kc) {
            int ab = ((kc << 6) + (lkE << 1)) ^ asx;
            bf16x8 af = __builtin_bit_cast(bf16x8, *(const u16x8*)(abase + ab));
            const u16* bk = bp + kt * 256 + kc * 32;
            bf16x8 b0 = __builtin_bit_cast(bf16x8, *(const u16x8*)(bk));
            bf16x8 b1 = __builtin_bit_cast(bf16x8, *(const u16x8*)(bk + (size_t)16 * 2048));
            acc[0] = __builtin_amdgcn_mfma_f32_16x16x32_bf16(af, b0, acc[0], 0, 0, 0);
            acc[1] = __builtin_amdgcn_mfma_f32_16x16x32_bf16(af, b1, acc[1], 0, 0, 0);
        }
        __syncthreads();             // all waves done reading Xb[kt&1]
        if (kt + 1 < 8) {
            char* dst = (char*)&Xb[(kt & 1) ^ 1][0][0];
            *(u16x8*)(dst + wb0) = pack8u(v0, v1);
            *(u16x8*)(dst + wb1) = pack8u(v2, v3);
            __syncthreads();         // next chunk staged for all
        }
    }

    // epilogue: Y[row][col] bf16; row = r0 + wr*16 + (lane>>4)*4 + r; col = jc*32 + jj*16 + lm
    u16* yw = Y + (size_t)(r0 + wr * 16 + ((lane >> 4) << 2)) * 128 + jc * 32 + lm;
#pragma unroll
    for (int jj = 0; jj < 2; ++jj) {
        f32x4 v = acc[jj];
#pragma unroll
        for (int r = 0; r < 4; ++r)
            yw[(size_t)r * 128 + jj * 16] = f2bf(v[r]);
    }
}

// ---------------- K2R: per block (512 thr, 8 waves), 32 rows; Y -> Yl; out 32x2048.
// (out-write path measured at ~6.7 TB/s; stage A now a single contiguous Y read)
__global__ __launch_bounds__(512) void k2r_kernel(const u16* __restrict__ Y,
                                                  const u16* __restrict__ H34T,
                                                  float* __restrict__ out) {
    __shared__ u16 Yl[32][136];   // 8.5 KB
    int tid = threadIdx.x, lane = tid & 63, w = tid >> 6;
    int lm = lane & 15, lkE = (lane >> 4) << 3;
    int r0 = blockIdx.x * 32;

    // ---- stage A: copy Y[32][128] into LDS (contiguous u16x8 per thread)
    {
        int row0 = tid >> 4;            // 0..31
        int ce = (tid & 15) << 3;       // 0..120
        *(u16x8*)&Yl[row0][ce] = *(const u16x8*)(Y + (size_t)(r0 + row0) * 128 + ce);
    }
    __syncthreads();

    // ---- stage B: wave w -> out cols [w*256, w*256+256); p = w>>2, ch = (w&3)*256
    int p = w >> 2, ch = (w & 3) << 8;
    bf16x8 ya[2][2];
#pragma unroll
    for (int rh = 0; rh < 2; ++rh)
#pragma unroll
        for (int kc = 0; kc < 2; ++kc)
            ya[rh][kc] = __builtin_bit_cast(bf16x8,
                *(const u16x8*)&Yl[rh * 16 + lm][p * 64 + kc * 32 + lkE]);

    const u16* hB = H34T + (size_t)(ch + lm) * 64 + lkE;
    float* cW = out + (size_t)(r0 + ((lane >> 4) << 2)) * 2048 + (w << 8) + lm;

#pragma unroll 4
    for (int cf = 0; cf < 16; ++cf) {
        const u16* hr = hB + (size_t)cf * 1024;     // 16 H34T rows * 64
        bf16x8 h0 = __builtin_bit_cast(bf16x8, *(const u16x8*)(hr));
        bf16x8 h1 = __builtin_bit_cast(bf16x8, *(const u16x8*)(hr + 32));
        f32x4 a0 = (f32x4){0.f, 0.f, 0.f, 0.f};
        f32x4 a1 = (f32x4){0.f, 0.f, 0.f, 0.f};
        a0 = __builtin_amdgcn_mfma_f32_16x16x32_bf16(ya[0][0], h0, a0, 0, 0, 0);
        a0 = __builtin_amdgcn_mfma_f32_16x16x32_bf16(ya[0][1], h1, a0, 0, 0, 0);
        a1 = __builtin_amdgcn_mfma_f32_16x16x32_bf16(ya[1][0], h0, a1, 0, 0, 0);
        a1 = __builtin_amdgcn_mfma_f32_16x16x32_bf16(ya[1][1], h1, a1, 0, 0, 0);
#pragma unroll
        for (int r = 0; r < 4; ++r) {
            cW[(size_t)r * 2048 + cf * 16] = a0[r];
            cW[(size_t)(16 + r) * 2048 + cf * 16] = a1[r];
        }
    }
}

extern "C" void kernel_launch(void* const* d_in, const int* in_sizes, int n_in,
                              void* d_out, int out_size, void* d_ws, size_t ws_size,
                              hipStream_t stream) {
    const float* x  = (const float*)d_in[0];
    const float* f0 = (const float*)d_in[1];
    const float* f1 = (const float*)d_in[2];
    const float* f2 = (const float*)d_in[3];
    const float* f3 = (const float*)d_in[4];
    float* out = (float*)d_out;

    char* ws = (char*)d_ws;
    u16* H12bT = (u16*)ws;                    // 512 KB [128][2048] bf16
    u16* H34T  = (u16*)(ws + (512u << 10));   // 128 KB [1024][64] bf16
    u16* Y     = (u16*)(ws + (1u << 20));     // 2 MB   [8192][128] bf16
    if (ws_size < ((size_t)4 << 20)) return;

    prep_kernel<<<1280, 256, 0, stream>>>(f0, f1, f2, f3, H12bT, H34T);
    k1_kernel<<<256, 512, 0, stream>>>(x, H12bT, Y);
    k2r_kernel<<<256, 512, 0, stream>>>(Y, H34T, out);
}

// Round 18
// 49.855 us; speedup vs baseline: 1.3821x; 1.3821x over previous
//
#include <hip/hip_runtime.h>
#include <hip/hip_bf16.h>
#include <stdint.h>

typedef unsigned short u16;
typedef __attribute__((ext_vector_type(8))) unsigned short u16x8;
typedef __attribute__((ext_vector_type(8))) __bf16 bf16x8;
typedef __attribute__((ext_vector_type(4))) float f32x4;

__device__ __forceinline__ u16 f2bf(float f) {
    uint32_t u = __builtin_bit_cast(uint32_t, f);
    u = (u + 0x7fffu + ((u >> 16) & 1u)) >> 16;
    return (u16)u;
}

__device__ __forceinline__ float bf2f(u16 v) {
    return __builtin_bit_cast(float, (uint32_t)v << 16);
}

__device__ __forceinline__ bf16x8 cvt8(const float* p) {
    f32x4 a = *(const f32x4*)p;
    f32x4 b = *(const f32x4*)(p + 4);
    u16x8 o;
    o[0] = f2bf(a[0]); o[1] = f2bf(a[1]); o[2] = f2bf(a[2]); o[3] = f2bf(a[3]);
    o[4] = f2bf(b[0]); o[5] = f2bf(b[1]); o[6] = f2bf(b[2]); o[7] = f2bf(b[3]);
    return __builtin_bit_cast(bf16x8, o);
}

// ---------------- prep: H12bT [128][2048] bf16  +  H34T [1024][64] bf16 (one launch)
__global__ __launch_bounds__(256) void prep_kernel(const float* __restrict__ f0,
                                                   const float* __restrict__ f1,
                                                   const float* __restrict__ f2,
                                                   const float* __restrict__ f3,
                                                   u16* __restrict__ H12bT,
                                                   u16* __restrict__ H34T) {
    int gid = blockIdx.x * 256 + threadIdx.x;       // 0..327679
    if (gid < 262144) {
        int rc = gid >> 11;                          // p*64 + e
        int k  = gid & 2047;                         // i1*32 + j2
        int p = rc >> 6, e = rc & 63;
        int a = e >> 3, b = e & 7;
        int i1 = k >> 5, i2 = ((k & 31) << 1) | p;
        float s = 0.f;
#pragma unroll
        for (int m = 0; m < 8; m++)
            s += f0[a * 512 + i1 * 8 + m] * f1[m * 512 + i2 * 8 + b];
        H12bT[gid] = f2bf(s);
    } else {
        int g = gid - 262144;                        // 0..65535
        int c = g >> 6;
        int e = g & 63;
        int a = e >> 3, b = e & 7;
        int i3 = c >> 4, i4 = c & 15;
        float s = 0.f;
#pragma unroll
        for (int cc = 0; cc < 8; cc++)
            s += f2[b * 512 + i3 * 8 + cc] * f3[cc * 128 + i4 * 8 + a];
        H34T[c * 64 + e] = f2bf(s);
    }
}

// ---------------- K1: Ypb[ks] = bf16( x(256 rows, K-seg 256) @ H12bT^T )
// Best-measured variant (benched 49.49/49.70 us total): grid (32, 8),
// block 256 = 4 waves x 64 rows, acc[4][8], direct cvt8 x-reads.
// k1's ~33 us is a 6x-replicated empirical floor (see session journal):
// strided fragment gathers cap ~1.6 TB/s regardless of occupancy/ILP/staging.
__global__ __launch_bounds__(256) void k1_kernel(const float* __restrict__ x,
                                                 const u16* __restrict__ H12bT,
                                                 u16* __restrict__ Ypb) {
    int tid = threadIdx.x, lane = tid & 63, w = tid >> 6;
    int lm = lane & 15, lkE = (lane >> 4) << 3;
    int r0 = blockIdx.x * 256 + w * 64;
    int k0 = blockIdx.y * 256;

    f32x4 acc[4][8];
#pragma unroll
    for (int s = 0; s < 4; ++s)
#pragma unroll
        for (int j = 0; j < 8; ++j) acc[s][j] = (f32x4){0.f, 0.f, 0.f, 0.f};

    const float* xB = x + (size_t)(r0 + lm) * 2048 + k0 + lkE;
    const u16*  bP  = H12bT + (size_t)lm * 2048 + k0 + lkE;

#pragma unroll
    for (int kc = 0; kc < 8; ++kc) {
        int ko = kc * 32;
        bf16x8 a[4];
#pragma unroll
        for (int s = 0; s < 4; ++s)
            a[s] = cvt8(xB + (size_t)(s * 16) * 2048 + ko);
        bf16x8 bf[8];
#pragma unroll
        for (int j = 0; j < 8; ++j)
            bf[j] = __builtin_bit_cast(bf16x8, *(const u16x8*)(bP + (size_t)j * 16 * 2048 + ko));
#pragma unroll
        for (int j = 0; j < 8; ++j)
#pragma unroll
            for (int s = 0; s < 4; ++s)
                acc[s][j] = __builtin_amdgcn_mfma_f32_16x16x32_bf16(a[s], bf[j], acc[s][j], 0, 0, 0);
    }
    // Ypb[ks][row][col] bf16 ; row = r0 + s*16 + (lane>>4)*4 + r ; col = j*16 + lm
    u16* ywB = Ypb + (size_t)blockIdx.y * 1048576 + (size_t)(r0 + ((lane >> 4) << 2)) * 128 + lm;
#pragma unroll
    for (int s = 0; s < 4; ++s)
#pragma unroll
        for (int j = 0; j < 8; ++j) {
            f32x4 v = acc[s][j];
#pragma unroll
            for (int r = 0; r < 4; ++r)
                ywB[(size_t)(s * 16 + r) * 128 + j * 16] = f2bf(v[r]);
        }
}

// ---------------- K2R: per block (512 thr, 8 waves), 32 rows; reduce Ypb -> Yl; out 32x2048.
// Measured at write roofline (~80 MB at ~6.7 TB/s); unchanged.
__global__ __launch_bounds__(512) void k2r_kernel(const u16* __restrict__ Ypb,
                                                  const u16* __restrict__ H34T,
                                                  float* __restrict__ out) {
    __shared__ u16 Yl[32][136];   // 8.5 KB
    int tid = threadIdx.x, lane = tid & 63, w = tid >> 6;
    int lm = lane & 15, lkE = (lane >> 4) << 3;
    int r0 = blockIdx.x * 32;

    // ---- stage A: sum 8 partial slabs [32][128]; 512 thr x one u16x8 each per slab
    {
        int row0 = tid >> 4;            // 0..31
        int ce = (tid & 15) << 3;       // 0..120
        float s0[8];
#pragma unroll
        for (int e = 0; e < 8; ++e) s0[e] = 0.f;
#pragma unroll
        for (int ks = 0; ks < 8; ++ks) {
            const u16* b = Ypb + (size_t)ks * 1048576 + (size_t)(r0 + row0) * 128 + ce;
            u16x8 v = *(const u16x8*)b;
#pragma unroll
            for (int e = 0; e < 8; ++e) s0[e] += bf2f(v[e]);
        }
        u16x8 o;
#pragma unroll
        for (int e = 0; e < 8; ++e) o[e] = f2bf(s0[e]);
        *(u16x8*)&Yl[row0][ce] = o;
    }
    __syncthreads();

    // ---- stage B: wave w -> out cols [w*256, w*256+256); p = w>>2, ch = (w&3)*256
    int p = w >> 2, ch = (w & 3) << 8;
    bf16x8 ya[2][2];
#pragma unroll
    for (int rh = 0; rh < 2; ++rh)
#pragma unroll
        for (int kc = 0; kc < 2; ++kc)
            ya[rh][kc] = __builtin_bit_cast(bf16x8,
                *(const u16x8*)&Yl[rh * 16 + lm][p * 64 + kc * 32 + lkE]);

    const u16* hB = H34T + (size_t)(ch + lm) * 64 + lkE;
    float* cW = out + (size_t)(r0 + ((lane >> 4) << 2)) * 2048 + (w << 8) + lm;

#pragma unroll 4
    for (int cf = 0; cf < 16; ++cf) {
        const u16* hr = hB + (size_t)cf * 1024;     // 16 H34T rows * 64
        bf16x8 h0 = __builtin_bit_cast(bf16x8, *(const u16x8*)(hr));
        bf16x8 h1 = __builtin_bit_cast(bf16x8, *(const u16x8*)(hr + 32));
        f32x4 a0 = (f32x4){0.f, 0.f, 0.f, 0.f};
        f32x4 a1 = (f32x4){0.f, 0.f, 0.f, 0.f};
        a0 = __builtin_amdgcn_mfma_f32_16x16x32_bf16(ya[0][0], h0, a0, 0, 0, 0);
        a0 = __builtin_amdgcn_mfma_f32_16x16x32_bf16(ya[0][1], h1, a0, 0, 0, 0);
        a1 = __builtin_amdgcn_mfma_f32_16x16x32_bf16(ya[1][0], h0, a1, 0, 0, 0);
        a1 = __builtin_amdgcn_mfma_f32_16x16x32_bf16(ya[1][1], h1, a1, 0, 0, 0);
#pragma unroll
        for (int r = 0; r < 4; ++r) {
            cW[(size_t)r * 2048 + cf * 16] = a0[r];
            cW[(size_t)(16 + r) * 2048 + cf * 16] = a1[r];
        }
    }
}

extern "C" void kernel_launch(void* const* d_in, const int* in_sizes, int n_in,
                              void* d_out, int out_size, void* d_ws, size_t ws_size,
                              hipStream_t stream) {
    const float* x  = (const float*)d_in[0];
    const float* f0 = (const float*)d_in[1];
    const float* f1 = (const float*)d_in[2];
    const float* f2 = (const float*)d_in[3];
    const float* f3 = (const float*)d_in[4];
    float* out = (float*)d_out;

    char* ws = (char*)d_ws;
    u16* H12bT = (u16*)ws;                    // 512 KB [128][2048] bf16
    u16* H34T  = (u16*)(ws + (512u << 10));   // 128 KB [1024][64] bf16
    u16* Ypb   = (u16*)(ws + (1u << 20));     // 16 MB  [8][8192][128] bf16
    if (ws_size < ((size_t)18 << 20)) return;

    prep_kernel<<<1280, 256, 0, stream>>>(f0, f1, f2, f3, H12bT, H34T);
    k1_kernel<<<dim3(32, 8), 256, 0, stream>>>(x, H12bT, Ypb);
    k2r_kernel<<<256, 512, 0, stream>>>(Ypb, H34T, out);
}

// Round 19
// 47.605 us; speedup vs baseline: 1.4474x; 1.0473x over previous
//
#include <hip/hip_runtime.h>
#include <hip/hip_bf16.h>
#include <stdint.h>

typedef unsigned short u16;
typedef __attribute__((ext_vector_type(8))) unsigned short u16x8;
typedef __attribute__((ext_vector_type(8))) __bf16 bf16x8;
typedef __attribute__((ext_vector_type(4))) float f32x4;

__device__ __forceinline__ u16 f2bf(float f) {
    uint32_t u = __builtin_bit_cast(uint32_t, f);
    u = (u + 0x7fffu + ((u >> 16) & 1u)) >> 16;
    return (u16)u;
}

__device__ __forceinline__ float bf2f(u16 v) {
    return __builtin_bit_cast(float, (uint32_t)v << 16);
}

// ---------------- prep: H12bT [128][2048] bf16  +  H34T [1024][64] bf16 (one launch)
__global__ __launch_bounds__(256) void prep_kernel(const float* __restrict__ f0,
                                                   const float* __restrict__ f1,
                                                   const float* __restrict__ f2,
                                                   const float* __restrict__ f3,
                                                   u16* __restrict__ H12bT,
                                                   u16* __restrict__ H34T) {
    int gid = blockIdx.x * 256 + threadIdx.x;       // 0..327679
    if (gid < 262144) {
        int rc = gid >> 11;                          // p*64 + e
        int k  = gid & 2047;                         // i1*32 + j2
        int p = rc >> 6, e = rc & 63;
        int a = e >> 3, b = e & 7;
        int i1 = k >> 5, i2 = ((k & 31) << 1) | p;
        float s = 0.f;
#pragma unroll
        for (int m = 0; m < 8; m++)
            s += f0[a * 512 + i1 * 8 + m] * f1[m * 512 + i2 * 8 + b];
        H12bT[gid] = f2bf(s);
    } else {
        int g = gid - 262144;                        // 0..65535
        int c = g >> 6;
        int e = g & 63;
        int a = e >> 3, b = e & 7;
        int i3 = c >> 4, i4 = c & 15;
        float s = 0.f;
#pragma unroll
        for (int cc = 0; cc < 8; cc++)
            s += f2[b * 512 + i3 * 8 + cc] * f3[cc * 128 + i4 * 8 + a];
        H34T[c * 64 + e] = f2bf(s);
    }
}

// ---------------- K1: Ypb[ks] = bf16( x(256 rows, K-seg 256) @ H12bT^T )
// R16 geometry; inner loop rewritten with inline-asm global_load_dwordx4 +
// hand-counted s_waitcnt vmcnt(16) (T4): 16 loads of kc+1 stay in flight while
// kc computes. Compiler-visible loads were serialized to MLP=1 (~800cy each);
// asm loads cannot be sunk. Ping-pong SSA sets, all indices literal.
__global__ __launch_bounds__(256, 1) void k1_kernel(const float* __restrict__ x,
                                                    const u16* __restrict__ H12bT,
                                                    u16* __restrict__ Ypb) {
    int tid = threadIdx.x, lane = tid & 63, w = tid >> 6;
    int lm = lane & 15, lkE = (lane >> 4) << 3;
    int r0 = blockIdx.x * 256 + w * 64;
    int k0 = blockIdx.y * 256;

    f32x4 acc[4][8];
#pragma unroll
    for (int s = 0; s < 4; ++s)
#pragma unroll
        for (int j = 0; j < 8; ++j) acc[s][j] = (f32x4){0.f, 0.f, 0.f, 0.f};

    const float* xS[4];
    const u16*   bJ[8];
#pragma unroll
    for (int s = 0; s < 4; ++s)
        xS[s] = x + (size_t)(r0 + s * 16 + lm) * 2048 + k0 + lkE;
#pragma unroll
    for (int j = 0; j < 8; ++j)
        bJ[j] = H12bT + (size_t)(j * 16 + lm) * 2048 + k0 + lkE;

    f32x4 xa[2][4][2];   // [set][strip][half] — in-flight x
    u16x8 bb[2][8];      // [set][frag]       — in-flight B

#define ISSUE(set_, kc_) do { \
    _Pragma("unroll") \
    for (int s = 0; s < 4; ++s) { \
        asm volatile("global_load_dwordx4 %0, %1, off" \
                     : "=v"(xa[set_][s][0]) : "v"(xS[s] + (kc_) * 32)); \
        asm volatile("global_load_dwordx4 %0, %1, off" \
                     : "=v"(xa[set_][s][1]) : "v"(xS[s] + (kc_) * 32 + 4)); \
    } \
    _Pragma("unroll") \
    for (int j = 0; j < 8; ++j) { \
        asm volatile("global_load_dwordx4 %0, %1, off" \
                     : "=v"(bb[set_][j]) : "v"(bJ[j] + (kc_) * 32)); \
    } \
} while (0)

#define STEP(kc_, set_, nset_, WAITN) do { \
    if ((kc_) < 7) ISSUE(nset_, (kc_) + 1); \
    asm volatile("s_waitcnt vmcnt(" #WAITN ")" ::: "memory"); \
    __builtin_amdgcn_sched_barrier(0); \
    bf16x8 a_[4]; \
    _Pragma("unroll") \
    for (int s = 0; s < 4; ++s) { \
        f32x4 A0 = xa[set_][s][0], A1 = xa[set_][s][1]; \
        u16x8 o; \
        o[0] = f2bf(A0[0]); o[1] = f2bf(A0[1]); o[2] = f2bf(A0[2]); o[3] = f2bf(A0[3]); \
        o[4] = f2bf(A1[0]); o[5] = f2bf(A1[1]); o[6] = f2bf(A1[2]); o[7] = f2bf(A1[3]); \
        a_[s] = __builtin_bit_cast(bf16x8, o); \
    } \
    _Pragma("unroll") \
    for (int j = 0; j < 8; ++j) { \
        bf16x8 bfj = __builtin_bit_cast(bf16x8, bb[set_][j]); \
        _Pragma("unroll") \
        for (int s = 0; s < 4; ++s) \
            acc[s][j] = __builtin_amdgcn_mfma_f32_16x16x32_bf16(a_[s], bfj, acc[s][j], 0, 0, 0); \
    } \
} while (0)

    ISSUE(0, 0);
    STEP(0, 0, 1, 16);
    STEP(1, 1, 0, 16);
    STEP(2, 0, 1, 16);
    STEP(3, 1, 0, 16);
    STEP(4, 0, 1, 16);
    STEP(5, 1, 0, 16);
    STEP(6, 0, 1, 16);
    STEP(7, 1, 0, 0);
#undef ISSUE
#undef STEP

    // Ypb[ks][row][col] bf16 ; row = r0 + s*16 + (lane>>4)*4 + r ; col = j*16 + lm
    u16* ywB = Ypb + (size_t)blockIdx.y * 1048576 + (size_t)(r0 + ((lane >> 4) << 2)) * 128 + lm;
#pragma unroll
    for (int s = 0; s < 4; ++s)
#pragma unroll
        for (int j = 0; j < 8; ++j) {
            f32x4 v = acc[s][j];
#pragma unroll
            for (int r = 0; r < 4; ++r)
                ywB[(size_t)(s * 16 + r) * 128 + j * 16] = f2bf(v[r]);
        }
}

// ---------------- K2R: per block (512 thr, 8 waves), 32 rows; reduce Ypb -> Yl; out 32x2048.
// Measured at write roofline (~80 MB at ~6.7 TB/s); unchanged.
__global__ __launch_bounds__(512) void k2r_kernel(const u16* __restrict__ Ypb,
                                                  const u16* __restrict__ H34T,
                                                  float* __restrict__ out) {
    __shared__ u16 Yl[32][136];   // 8.5 KB
    int tid = threadIdx.x, lane = tid & 63, w = tid >> 6;
    int lm = lane & 15, lkE = (lane >> 4) << 3;
    int r0 = blockIdx.x * 32;

    // ---- stage A: sum 8 partial slabs [32][128]; 512 thr x one u16x8 each per slab
    {
        int row0 = tid >> 4;            // 0..31
        int ce = (tid & 15) << 3;       // 0..120
        float s0[8];
#pragma unroll
        for (int e = 0; e < 8; ++e) s0[e] = 0.f;
#pragma unroll
        for (int ks = 0; ks < 8; ++ks) {
            const u16* b = Ypb + (size_t)ks * 1048576 + (size_t)(r0 + row0) * 128 + ce;
            u16x8 v = *(const u16x8*)b;
#pragma unroll
            for (int e = 0; e < 8; ++e) s0[e] += bf2f(v[e]);
        }
        u16x8 o;
#pragma unroll
        for (int e = 0; e < 8; ++e) o[e] = f2bf(s0[e]);
        *(u16x8*)&Yl[row0][ce] = o;
    }
    __syncthreads();

    // ---- stage B: wave w -> out cols [w*256, w*256+256); p = w>>2, ch = (w&3)*256
    int p = w >> 2, ch = (w & 3) << 8;
    bf16x8 ya[2][2];
#pragma unroll
    for (int rh = 0; rh < 2; ++rh)
#pragma unroll
        for (int kc = 0; kc < 2; ++kc)
            ya[rh][kc] = __builtin_bit_cast(bf16x8,
                *(const u16x8*)&Yl[rh * 16 + lm][p * 64 + kc * 32 + lkE]);

    const u16* hB = H34T + (size_t)(ch + lm) * 64 + lkE;
    float* cW = out + (size_t)(r0 + ((lane >> 4) << 2)) * 2048 + (w << 8) + lm;

#pragma unroll 4
    for (int cf = 0; cf < 16; ++cf) {
        const u16* hr = hB + (size_t)cf * 1024;     // 16 H34T rows * 64
        bf16x8 h0 = __builtin_bit_cast(bf16x8, *(const u16x8*)(hr));
        bf16x8 h1 = __builtin_bit_cast(bf16x8, *(const u16x8*)(hr + 32));
        f32x4 a0 = (f32x4){0.f, 0.f, 0.f, 0.f};
        f32x4 a1 = (f32x4){0.f, 0.f, 0.f, 0.f};
        a0 = __builtin_amdgcn_mfma_f32_16x16x32_bf16(ya[0][0], h0, a0, 0, 0, 0);
        a0 = __builtin_amdgcn_mfma_f32_16x16x32_bf16(ya[0][1], h1, a0, 0, 0, 0);
        a1 = __builtin_amdgcn_mfma_f32_16x16x32_bf16(ya[1][0], h0, a1, 0, 0, 0);
        a1 = __builtin_amdgcn_mfma_f32_16x16x32_bf16(ya[1][1], h1, a1, 0, 0, 0);
#pragma unroll
        for (int r = 0; r < 4; ++r) {
            cW[(size_t)r * 2048 + cf * 16] = a0[r];
            cW[(size_t)(16 + r) * 2048 + cf * 16] = a1[r];
        }
    }
}

extern "C" void kernel_launch(void* const* d_in, const int* in_sizes, int n_in,
                              void* d_out, int out_size, void* d_ws, size_t ws_size,
                              hipStream_t stream) {
    const float* x  = (const float*)d_in[0];
    const float* f0 = (const float*)d_in[1];
    const float* f1 = (const float*)d_in[2];
    const float* f2 = (const float*)d_in[3];
    const float* f3 = (const float*)d_in[4];
    float* out = (float*)d_out;

    char* ws = (char*)d_ws;
    u16* H12bT = (u16*)ws;                    // 512 KB [128][2048] bf16
    u16* H34T  = (u16*)(ws + (512u << 10));   // 128 KB [1024][64] bf16
    u16* Ypb   = (u16*)(ws + (1u << 20));     // 16 MB  [8][8192][128] bf16
    if (ws_size < ((size_t)18 << 20)) return;

    prep_kernel<<<1280, 256, 0, stream>>>(f0, f1, f2, f3, H12bT, H34T);
    k1_kernel<<<dim3(32, 8), 256, 0, stream>>>(x, H12bT, Ypb);
    k2r_kernel<<<256, 512, 0, stream>>>(Ypb, H34T, out);
}